// Round 19
// baseline (303.563 us; speedup 1.0000x reference)
//
#include <hip/hip_runtime.h>
#include <math.h>

#define NEG_SLOPE 0.2f
#define BIN_SHIFT 8          // dst bin = dst >> 8  (196 bins for N=50000)
#define CHUNK 2048           // edges per block in bin_scatter
#define BINCAP 16384         // fixed pairs capacity per bin

typedef __fp16 f16x4 __attribute__((ext_vector_type(4)));
typedef __fp16 f16x8 __attribute__((ext_vector_type(8)));
typedef float  f32x4 __attribute__((ext_vector_type(4)));

__device__ __forceinline__ unsigned pkh_rne(float a, float b) {
    __fp16 ha = (__fp16)a, hb = (__fp16)b;
    unsigned short ua, ub;
    __builtin_memcpy(&ua, &ha, 2);
    __builtin_memcpy(&ub, &hb, 2);
    return (unsigned)ua | ((unsigned)ub << 16);
}

// acc += f16(lo/hi of h) * w   (f32 accumulate)
#define FMAMIX_LO(a, h, w) asm("v_fma_mix_f32 %0, %1, %2, %0 op_sel:[0,0,0] op_sel_hi:[1,0,0]" : "+v"(a) : "v"(h), "v"(w))
#define FMAMIX_HI(a, h, w) asm("v_fma_mix_f32 %0, %1, %2, %0 op_sel:[1,0,0] op_sel_hi:[1,0,0]" : "+v"(a) : "v"(h), "v"(w))

// ---- MFMA f16 GEMM with fused node_dots epilogue ---------------------------
template <bool BX>
__global__ __launch_bounds__(256)
void gemm128_mfma(const unsigned short* __restrict__ Xin,
                  const float* __restrict__ pos, const int* __restrict__ z,
                  const float* __restrict__ emb,
                  const float* __restrict__ W,
                  const float* __restrict__ a_s, const float* __restrict__ a_d,
                  unsigned short* __restrict__ Yh,
                  float* __restrict__ ssrc, float* __restrict__ sdst, int n) {
    __shared__ unsigned short WT[128 * 128];  // 32 KB
    __shared__ unsigned short Xh[64 * 128];   // 16 KB
    __shared__ float As[128], Ad[128];
    __shared__ int zl[64];
    int tid = threadIdx.x;
    if (tid < 128) As[tid] = a_s[tid];
    else           Ad[tid - 128] = a_d[tid - 128];
    int r0 = blockIdx.x * 64;
    if (BX && tid < 64) zl[tid] = (r0 + tid < n) ? z[r0 + tid] : 0;

    #pragma unroll
    for (int it = 0; it < 32; ++it) {
        int id = it * 256 + tid;
        int col = id & 127, kp = id >> 7;
        float w0 = W[(size_t)(2 * kp) * 128 + col];
        float w1 = W[(size_t)(2 * kp + 1) * 128 + col];
        int byte = (col * 256 + kp * 4) ^ ((col & 7) << 3);
        *(unsigned*)((char*)WT + byte) = pkh_rne(w0, w1);
    }
    if (BX) __syncthreads();   // zl ready
    #pragma unroll
    for (int it = 0; it < 16; ++it) {
        int id = it * 256 + tid;
        int row = id >> 6, c = id & 63;
        int grow = r0 + row;
        unsigned v;
        if (BX) {
            float f0 = 0.f, f1 = 0.f;
            if (grow < n) {
                int zn = zl[row];
                int k0 = 2 * c, k1 = 2 * c + 1;
                f0 = (k0 < 3) ? pos[(size_t)grow * 3 + k0] : emb[(size_t)zn * 125 + (k0 - 3)];
                f1 = (k1 < 3) ? pos[(size_t)grow * 3 + k1] : emb[(size_t)zn * 125 + (k1 - 3)];
            }
            v = pkh_rne(f0, f1);
        } else {
            v = (grow < n) ? *(const unsigned*)(Xin + (size_t)grow * 128 + 2 * c) : 0u;
        }
        int byte = (row * 256 + c * 4) ^ ((row & 7) << 3);
        *(unsigned*)((char*)Xh + byte) = v;
    }
    __syncthreads();

    int lane = tid & 63, wv = tid >> 6;
    int rL = (wv << 4) + (lane & 15);
    int kg = lane >> 4;
    f32x4 acc[8];
    #pragma unroll
    for (int t = 0; t < 8; ++t) acc[t] = (f32x4){0.f, 0.f, 0.f, 0.f};

    #pragma unroll
    for (int k0 = 0; k0 < 128; k0 += 32) {
        int abase = rL * 256;
        int aswz = (rL & 7) << 3;
        f16x4 alo = *(f16x4*)((char*)Xh + ((abase + (k0 + kg * 4) * 2) ^ aswz));
        f16x4 ahi = *(f16x4*)((char*)Xh + ((abase + (k0 + 16 + kg * 4) * 2) ^ aswz));
        f16x8 a = {alo[0], alo[1], alo[2], alo[3], ahi[0], ahi[1], ahi[2], ahi[3]};
        #pragma unroll
        for (int t = 0; t < 8; ++t) {
            int colL = (t << 4) + (lane & 15);
            int bbase = colL * 256;
            int bswz = (colL & 7) << 3;
            f16x4 blo = *(f16x4*)((char*)WT + ((bbase + (k0 + kg * 4) * 2) ^ bswz));
            f16x4 bhi = *(f16x4*)((char*)WT + ((bbase + (k0 + 16 + kg * 4) * 2) ^ bswz));
            f16x8 b = {blo[0], blo[1], blo[2], blo[3], bhi[0], bhi[1], bhi[2], bhi[3]};
            acc[t] = __builtin_amdgcn_mfma_f32_16x16x32_f16(a, b, acc[t], 0, 0, 0);
        }
    }

    int rowBase = r0 + (wv << 4) + kg * 4;
    float ds[4] = {0.f, 0.f, 0.f, 0.f}, dd[4] = {0.f, 0.f, 0.f, 0.f};
    #pragma unroll
    for (int t = 0; t < 8; ++t) {
        int colA = (t << 4) + (lane & 15);
        float as = As[colA], ad = Ad[colA];
        #pragma unroll
        for (int i = 0; i < 4; ++i) {
            int rowA = rowBase + i;
            if (rowA < n) {
                __fp16 hv = (__fp16)acc[t][i];
                *(__fp16*)(Yh + (size_t)rowA * 128 + colA) = hv;
            }
            ds[i] += acc[t][i] * as;
            dd[i] += acc[t][i] * ad;
        }
    }
    #pragma unroll
    for (int o = 1; o < 16; o <<= 1) {
        #pragma unroll
        for (int i = 0; i < 4; ++i) {
            ds[i] += __shfl_xor(ds[i], o);
            dd[i] += __shfl_xor(dd[i], o);
        }
    }
    if ((lane & 15) == 0) {
        #pragma unroll
        for (int i = 0; i < 4; ++i) {
            int rowA = rowBase + i;
            if (rowA < n) { ssrc[rowA] = ds[i]; sdst[rowA] = dd[i]; }
        }
    }
}

// ------------- CSR build: fixed-capacity bins, binCur zeroed by memset ------

// pairs packed: (dst & 255) << 24 | src; bin b region at b*BINCAP; binCur = count
__global__ void bin_scatter(const int* __restrict__ ei, int E, int n, int nbins,
                            int* __restrict__ binCursor, unsigned* __restrict__ pairs) {
    __shared__ int h[256], cur[256];
    int t = threadIdx.x;
    h[t] = 0;
    __syncthreads();
    int lo = blockIdx.x * CHUNK, hi = min(lo + CHUNK, E + n);
    for (int e = lo + t; e < hi; e += 256) {
        int d = (e < E) ? ei[E + e] : (e - E);
        atomicAdd(&h[d >> BIN_SHIFT], 1);
    }
    __syncthreads();
    if (t < nbins) cur[t] = (t << 14) + (h[t] ? atomicAdd(&binCursor[t], h[t]) : 0);
    __syncthreads();
    for (int e = lo + t; e < hi; e += 256) {
        int s, d;
        if (e < E) { s = ei[e]; d = ei[E + e]; } else { s = d = e - E; }
        int p = atomicAdd(&cur[d >> BIN_SHIFT], 1);
        pairs[p] = ((unsigned)(d & 255) << 24) | (unsigned)s;
    }
}

// 512 threads; derives its own binBase by scanning binCur in LDS (no bin_scan kernel)
__global__ __launch_bounds__(512)
void bin_finalize(const unsigned* __restrict__ pairs, const int* __restrict__ binCur,
                  int* __restrict__ rowptr, int* __restrict__ csr_src,
                  int n, int nbins, int Etot) {
    int b = blockIdx.x;
    int t = threadIdx.x;
    __shared__ int h[256], s[256], cur[256];
    __shared__ int sb_base, sb_cnt;

    // scan binCur -> base for this bin
    if (t < 256) s[t] = (t < nbins) ? binCur[t] : 0;
    __syncthreads();
    for (int o = 1; o < 256; o <<= 1) {
        int tv = (t >= o && t < 256) ? s[t - o] : 0;
        __syncthreads();
        if (t < 256) s[t] += tv;
        __syncthreads();
    }
    if (t == 0) {
        sb_cnt = binCur[b];
        sb_base = s[b] - sb_cnt;       // exclusive prefix
        if (b == nbins - 1) rowptr[n] = Etot;
    }
    __syncthreads();
    int base = sb_base, cnt = sb_cnt;
    int lop = b * BINCAP;
    int d0 = b << BIN_SHIFT;
    int nd = min(256, n - d0);

    if (t < 256) h[t] = 0;
    __syncthreads();
    for (int i = lop + t; i < lop + cnt; i += 512)
        atomicAdd(&h[pairs[i] >> 24], 1);
    __syncthreads();
    if (t < 256) s[t] = h[t];
    __syncthreads();
    for (int o = 1; o < 256; o <<= 1) {
        int tv = (t >= o && t < 256) ? s[t - o] : 0;
        __syncthreads();
        if (t < 256) s[t] += tv;
        __syncthreads();
    }
    if (t < 256) {
        int excl = base + s[t] - h[t];
        if (t < nd) rowptr[d0 + t] = excl;
        cur[t] = excl;
    }
    __syncthreads();
    for (int i = lop + t; i < lop + cnt; i += 512) {
        unsigned pr = pairs[i];
        int p = atomicAdd(&cur[pr >> 24], 1);
        csr_src[p] = (int)(pr & 0xFFFFFF);
    }
}

// ------------- fused GAT aggregation: one wave per dst node -----------------
// lane = 16*g + c; subgroup g walks edges, chunk c covers 8 f16 feats (uint4).
__global__ void gat_gather(const int* __restrict__ rowptr, const int* __restrict__ csr_src,
                           const float* __restrict__ ssrc, const float* __restrict__ sdst,
                           const unsigned short* __restrict__ hu, const float* __restrict__ bias,
                           unsigned* __restrict__ outh, int n) {
    __shared__ uint2 stage[4][64];
    int wv = threadIdx.x >> 6;
    int wid = (blockIdx.x * blockDim.x + threadIdx.x) >> 6;
    int lane = threadIdx.x & 63;
    if (wid >= n) return;
    int beg = rowptr[wid], end = rowptr[wid + 1];
    float sd = sdst[wid];
    int g = lane >> 4;
    int c = lane & 15;

    int src0 = 0; float v0 = -INFINITY;
    {
        int i = beg + lane;
        if (i < end) {
            src0 = csr_src[i];
            float t = ssrc[src0] + sd;
            v0 = t > 0.f ? t : NEG_SLOPE * t;
        }
    }
    float m = v0;
    for (int base = beg + 64; base < end; base += 64) {
        int i = base + lane;
        float s = -INFINITY;
        if (i < end) {
            float t = ssrc[csr_src[i]] + sd;
            s = t > 0.f ? t : NEG_SLOPE * t;
        }
        m = fmaxf(m, s);
    }
    #pragma unroll
    for (int o = 32; o; o >>= 1) m = fmaxf(m, __shfl_xor(m, o));

    float acc[8];
    #pragma unroll
    for (int k = 0; k < 8; ++k) acc[k] = 0.f;
    float den = 0.f;

    for (int base = beg; base < end; base += 64) {
        int cnt = min(64, end - base);
        float w = 0.f; int src = 0;
        if (base == beg) {
            src = src0;
            w = (lane < cnt) ? expf(v0 - m) : 0.f;
        } else {
            int i = base + lane;
            if (i < end) {
                src = csr_src[i];
                float t = ssrc[src] + sd;
                t = t > 0.f ? t : NEG_SLOPE * t;
                w = expf(t - m);
            }
        }
        den += w;
        stage[wv][lane] = make_uint2(__float_as_uint(w), (unsigned)src);
        asm volatile("s_waitcnt lgkmcnt(0)" ::: "memory");
        int steps = (cnt + 3) >> 2;
        #pragma unroll 4
        for (int j = 0; j < steps; ++j) {
            uint2 pr = stage[wv][j * 4 + g];
            float wj = __uint_as_float(pr.x);
            const uint4 hv = *(const uint4*)(hu + (size_t)pr.y * 128 + c * 8);
            FMAMIX_LO(acc[0], hv.x, wj); FMAMIX_HI(acc[1], hv.x, wj);
            FMAMIX_LO(acc[2], hv.y, wj); FMAMIX_HI(acc[3], hv.y, wj);
            FMAMIX_LO(acc[4], hv.z, wj); FMAMIX_HI(acc[5], hv.z, wj);
            FMAMIX_LO(acc[6], hv.w, wj); FMAMIX_HI(acc[7], hv.w, wj);
        }
    }
    #pragma unroll
    for (int o = 32; o; o >>= 1) den += __shfl_xor(den, o);
    #pragma unroll
    for (int k = 0; k < 8; ++k) {
        acc[k] += __shfl_xor(acc[k], 16);
        acc[k] += __shfl_xor(acc[k], 32);
    }
    if (g == 0) {
        float o8[8];
        #pragma unroll
        for (int k = 0; k < 8; ++k) {
            float v = acc[k] / den + bias[c * 8 + k];
            o8[k] = v > 0.f ? v : (expf(v) - 1.f);
        }
        uint4 u = make_uint4(pkh_rne(o8[0], o8[1]), pkh_rne(o8[2], o8[3]),
                             pkh_rne(o8[4], o8[5]), pkh_rne(o8[6], o8[7]));
        *(uint4*)(outh + (size_t)wid * 64 + c * 4) = u;
    }
}

// ------- pooling: partial sums + last-block final GEMM (one kernel) ---------
__global__ void pool_fused(const unsigned short* __restrict__ y, const int* __restrict__ batch,
                           float* __restrict__ gsum, int* __restrict__ ticket,
                           const float* __restrict__ Wlin, const float* __restrict__ blin,
                           float* __restrict__ out, int n, int G) {
    int g = blockIdx.x >> 2, seg = blockIdx.x & 3;
    int lo = 0, hi = n;
    while (lo < hi) { int mid = (lo + hi) >> 1; if (batch[mid] < g) lo = mid + 1; else hi = mid; }
    int beg = lo;
    hi = n;
    while (lo < hi) { int mid = (lo + hi) >> 1; if (batch[mid] < g + 1) lo = mid + 1; else hi = mid; }
    int end = lo;

    int c = threadIdx.x & 127, sub = threadIdx.x >> 7;
    float acc = 0.f;
    for (int node = beg + seg + 4 * sub; node < end; node += 8) {
        unsigned short u = y[(size_t)node * 128 + c];
        __fp16 hval;
        __builtin_memcpy(&hval, &u, 2);
        acc += (float)hval;
    }

    __shared__ float ls[2][128];
    ls[sub][c] = acc;
    __syncthreads();
    if (sub == 0) atomicAdd(&gsum[g * 128 + c], ls[0][c] + ls[1][c]);

    // ---- last-block final phase ----
    __shared__ bool is_last;
    __threadfence();
    if (threadIdx.x == 0) is_last = (atomicAdd(ticket, 1) == gridDim.x - 1);
    __syncthreads();
    if (!is_last) return;

    __shared__ float Wl[128 * 32];
    __shared__ float gs[64 * 128 > 8192 ? 8192 : 8192];  // G*128 = 8192 floats (32KB)
    __shared__ int cnts[64];
    int t = threadIdx.x;
    for (int i = t; i < 128 * 32; i += 256) Wl[i] = Wlin[i];
    // device-scope atomic reads of gsum (safe across XCD L2s)
    for (int i = t; i < G * 128; i += 256) gs[i] = atomicAdd(&gsum[i], 0.f);
    if (t < G) {
        int gg = t;
        int l2 = 0, h2 = n;
        while (l2 < h2) { int mid = (l2 + h2) >> 1; if (batch[mid] < gg) l2 = mid + 1; else h2 = mid; }
        int bg = l2;
        h2 = n;
        while (l2 < h2) { int mid = (l2 + h2) >> 1; if (batch[mid] < gg + 1) l2 = mid + 1; else h2 = mid; }
        cnts[gg] = l2 - bg;
    }
    __syncthreads();
    for (int idx = t; idx < G * 32; idx += 256) {
        int gg = idx >> 5, oc = idx & 31;
        int cnt = cnts[gg];
        float o = 0.f;
        if (cnt > 0) {
            float inv = 1.f / (float)cnt;
            float a2 = 0.f;
            #pragma unroll 8
            for (int k = 0; k < 128; ++k) a2 += gs[gg * 128 + k] * Wl[k * 32 + oc];
            o = a2 * inv + blin[oc];
        }
        out[idx] = o;
    }
}

extern "C" void kernel_launch(void* const* d_in, const int* in_sizes, int n_in,
                              void* d_out, int out_size, void* d_ws, size_t ws_size,
                              hipStream_t stream) {
    const float* pos  = (const float*)d_in[0];
    const int*   z    = (const int*)d_in[1];
    const int*   ei   = (const int*)d_in[2];
    const int*   batch= (const int*)d_in[3];
    const float* emb  = (const float*)d_in[4];
    const float* W1   = (const float*)d_in[5];
    const float* a1s  = (const float*)d_in[6];
    const float* a1d  = (const float*)d_in[7];
    const float* b1   = (const float*)d_in[8];
    const float* W2   = (const float*)d_in[9];
    const float* a2s  = (const float*)d_in[10];
    const float* a2d  = (const float*)d_in[11];
    const float* b2   = (const float*)d_in[12];
    const float* Wlin = (const float*)d_in[13];
    const float* blin = (const float*)d_in[14];

    const int N = in_sizes[0] / 3;        // 50000
    const int E = in_sizes[2] / 2;        // 1600000
    const int Etot = E + N;
    const int G = out_size / 32;          // 64
    const int nbins = ((N - 1) >> BIN_SHIFT) + 1;   // 196

    char* ws = (char*)d_ws;
    size_t pairsB = (size_t)nbins * BINCAP * sizeof(unsigned);   // 12.85MB, 256B-aligned
    unsigned* pairs = (unsigned*)ws;
    unsigned short* xh  = (unsigned short*)(ws + pairsB);        // f16 out1 / out2
    unsigned short* hbf = xh + (size_t)N * 128;                  // f16 h
    float* ssrc   = (float*)(hbf + (size_t)N * 128);
    float* sdst   = ssrc + N;
    int*   rowptr = (int*)(sdst + N);              // N+1
    int*   binCur = rowptr + N + 1;                // 256 (slot 255 = pool ticket)
    float* gsum   = (float*)(binCur + 256);        // G*128 (memset with binCur)
    int*   csrs   = (int*)(gsum + (size_t)G * 128);// Etot
    int*   ticket = binCur + 255;                  // unused bin slot (nbins=196)

    const int TB = 256;
    dim3 blk(TB);
    int gGemm  = (N + 63) / 64;
    int gGat   = (N + 3) / 4;
    int nchunk = (Etot + CHUNK - 1) / CHUNK;       // 807

    // ---------- CSR build (binCur + gsum zeroed in one memset) ----------
    hipMemsetAsync(binCur, 0, (256 + (size_t)G * 128) * sizeof(int), stream);
    bin_scatter<<<nchunk, blk, 0, stream>>>(ei, E, N, nbins, binCur, pairs);
    bin_finalize<<<nbins, dim3(512), 0, stream>>>(pairs, binCur, rowptr, csrs, N, nbins, Etot);

    // ---------- layer 1 (build_x fused into GEMM staging) ----------
    gemm128_mfma<true><<<gGemm, blk, 0, stream>>>(nullptr, pos, z, emb, W1, a1s, a1d,
                                                  hbf, ssrc, sdst, N);
    gat_gather<<<gGat, blk, 0, stream>>>(rowptr, csrs, ssrc, sdst, hbf, b1, (unsigned*)xh, N);

    // ---------- layer 2 ----------
    gemm128_mfma<false><<<gGemm, blk, 0, stream>>>(xh, nullptr, nullptr, nullptr, W2, a2s, a2d,
                                                   hbf, ssrc, sdst, N);
    gat_gather<<<gGat, blk, 0, stream>>>(rowptr, csrs, ssrc, sdst, hbf, b2, (unsigned*)xh, N);

    // ---------- pool (partial + last-block final) ----------
    pool_fused<<<G * 4, blk, 0, stream>>>(xh, batch, gsum, ticket, Wlin, blin,
                                          (float*)d_out, N, G);
}

// Round 20
// 268.106 us; speedup vs baseline: 1.1322x; 1.1322x over previous
//
#include <hip/hip_runtime.h>
#include <math.h>

#define NEG_SLOPE 0.2f
#define BIN_SHIFT 8          // dst bin = dst >> 8  (196 bins for N=50000)
#define CHUNK 2048           // edges per block in bin_scatter
#define BINCAP 16384         // fixed pairs capacity per bin

typedef __fp16 f16x4 __attribute__((ext_vector_type(4)));
typedef __fp16 f16x8 __attribute__((ext_vector_type(8)));
typedef float  f32x4 __attribute__((ext_vector_type(4)));

__device__ __forceinline__ unsigned pkh_rne(float a, float b) {
    __fp16 ha = (__fp16)a, hb = (__fp16)b;
    unsigned short ua, ub;
    __builtin_memcpy(&ua, &ha, 2);
    __builtin_memcpy(&ub, &hb, 2);
    return (unsigned)ua | ((unsigned)ub << 16);
}

// acc += f16(lo/hi of h) * w   (f32 accumulate)
#define FMAMIX_LO(a, h, w) asm("v_fma_mix_f32 %0, %1, %2, %0 op_sel:[0,0,0] op_sel_hi:[1,0,0]" : "+v"(a) : "v"(h), "v"(w))
#define FMAMIX_HI(a, h, w) asm("v_fma_mix_f32 %0, %1, %2, %0 op_sel:[1,0,0] op_sel_hi:[1,0,0]" : "+v"(a) : "v"(h), "v"(w))

// ---- MFMA f16 GEMM with fused node_dots epilogue ---------------------------
template <bool BX>
__global__ __launch_bounds__(256)
void gemm128_mfma(const unsigned short* __restrict__ Xin,
                  const float* __restrict__ pos, const int* __restrict__ z,
                  const float* __restrict__ emb,
                  const float* __restrict__ W,
                  const float* __restrict__ a_s, const float* __restrict__ a_d,
                  unsigned short* __restrict__ Yh,
                  float* __restrict__ ssrc, float* __restrict__ sdst, int n) {
    __shared__ unsigned short WT[128 * 128];  // 32 KB
    __shared__ unsigned short Xh[64 * 128];   // 16 KB
    __shared__ float As[128], Ad[128];
    __shared__ int zl[64];
    int tid = threadIdx.x;
    if (tid < 128) As[tid] = a_s[tid];
    else           Ad[tid - 128] = a_d[tid - 128];
    int r0 = blockIdx.x * 64;
    if (BX && tid < 64) zl[tid] = (r0 + tid < n) ? z[r0 + tid] : 0;

    #pragma unroll
    for (int it = 0; it < 32; ++it) {
        int id = it * 256 + tid;
        int col = id & 127, kp = id >> 7;
        float w0 = W[(size_t)(2 * kp) * 128 + col];
        float w1 = W[(size_t)(2 * kp + 1) * 128 + col];
        int byte = (col * 256 + kp * 4) ^ ((col & 7) << 3);
        *(unsigned*)((char*)WT + byte) = pkh_rne(w0, w1);
    }
    if (BX) __syncthreads();   // zl ready
    #pragma unroll
    for (int it = 0; it < 16; ++it) {
        int id = it * 256 + tid;
        int row = id >> 6, c = id & 63;
        int grow = r0 + row;
        unsigned v;
        if (BX) {
            float f0 = 0.f, f1 = 0.f;
            if (grow < n) {
                int zn = zl[row];
                int k0 = 2 * c, k1 = 2 * c + 1;
                f0 = (k0 < 3) ? pos[(size_t)grow * 3 + k0] : emb[(size_t)zn * 125 + (k0 - 3)];
                f1 = (k1 < 3) ? pos[(size_t)grow * 3 + k1] : emb[(size_t)zn * 125 + (k1 - 3)];
            }
            v = pkh_rne(f0, f1);
        } else {
            v = (grow < n) ? *(const unsigned*)(Xin + (size_t)grow * 128 + 2 * c) : 0u;
        }
        int byte = (row * 256 + c * 4) ^ ((row & 7) << 3);
        *(unsigned*)((char*)Xh + byte) = v;
    }
    __syncthreads();

    int lane = tid & 63, wv = tid >> 6;
    int rL = (wv << 4) + (lane & 15);
    int kg = lane >> 4;
    f32x4 acc[8];
    #pragma unroll
    for (int t = 0; t < 8; ++t) acc[t] = (f32x4){0.f, 0.f, 0.f, 0.f};

    #pragma unroll
    for (int k0 = 0; k0 < 128; k0 += 32) {
        int abase = rL * 256;
        int aswz = (rL & 7) << 3;
        f16x4 alo = *(f16x4*)((char*)Xh + ((abase + (k0 + kg * 4) * 2) ^ aswz));
        f16x4 ahi = *(f16x4*)((char*)Xh + ((abase + (k0 + 16 + kg * 4) * 2) ^ aswz));
        f16x8 a = {alo[0], alo[1], alo[2], alo[3], ahi[0], ahi[1], ahi[2], ahi[3]};
        #pragma unroll
        for (int t = 0; t < 8; ++t) {
            int colL = (t << 4) + (lane & 15);
            int bbase = colL * 256;
            int bswz = (colL & 7) << 3;
            f16x4 blo = *(f16x4*)((char*)WT + ((bbase + (k0 + kg * 4) * 2) ^ bswz));
            f16x4 bhi = *(f16x4*)((char*)WT + ((bbase + (k0 + 16 + kg * 4) * 2) ^ bswz));
            f16x8 b = {blo[0], blo[1], blo[2], blo[3], bhi[0], bhi[1], bhi[2], bhi[3]};
            acc[t] = __builtin_amdgcn_mfma_f32_16x16x32_f16(a, b, acc[t], 0, 0, 0);
        }
    }

    int rowBase = r0 + (wv << 4) + kg * 4;
    float ds[4] = {0.f, 0.f, 0.f, 0.f}, dd[4] = {0.f, 0.f, 0.f, 0.f};
    #pragma unroll
    for (int t = 0; t < 8; ++t) {
        int colA = (t << 4) + (lane & 15);
        float as = As[colA], ad = Ad[colA];
        #pragma unroll
        for (int i = 0; i < 4; ++i) {
            int rowA = rowBase + i;
            if (rowA < n) {
                __fp16 hv = (__fp16)acc[t][i];
                *(__fp16*)(Yh + (size_t)rowA * 128 + colA) = hv;
            }
            ds[i] += acc[t][i] * as;
            dd[i] += acc[t][i] * ad;
        }
    }
    #pragma unroll
    for (int o = 1; o < 16; o <<= 1) {
        #pragma unroll
        for (int i = 0; i < 4; ++i) {
            ds[i] += __shfl_xor(ds[i], o);
            dd[i] += __shfl_xor(dd[i], o);
        }
    }
    if ((lane & 15) == 0) {
        #pragma unroll
        for (int i = 0; i < 4; ++i) {
            int rowA = rowBase + i;
            if (rowA < n) { ssrc[rowA] = ds[i]; sdst[rowA] = dd[i]; }
        }
    }
}

// ------------- CSR build: fixed-capacity bins, binCur zeroed by memset ------

// pairs packed: (dst & 255) << 24 | src; bin b region at b*BINCAP; binCur = count
__global__ void bin_scatter(const int* __restrict__ ei, int E, int n, int nbins,
                            int* __restrict__ binCursor, unsigned* __restrict__ pairs) {
    __shared__ int h[256], cur[256];
    int t = threadIdx.x;
    h[t] = 0;
    __syncthreads();
    int lo = blockIdx.x * CHUNK, hi = min(lo + CHUNK, E + n);
    for (int e = lo + t; e < hi; e += 256) {
        int d = (e < E) ? ei[E + e] : (e - E);
        atomicAdd(&h[d >> BIN_SHIFT], 1);
    }
    __syncthreads();
    if (t < nbins) cur[t] = (t << 14) + (h[t] ? atomicAdd(&binCursor[t], h[t]) : 0);
    __syncthreads();
    for (int e = lo + t; e < hi; e += 256) {
        int s, d;
        if (e < E) { s = ei[e]; d = ei[E + e]; } else { s = d = e - E; }
        int p = atomicAdd(&cur[d >> BIN_SHIFT], 1);
        pairs[p] = ((unsigned)(d & 255) << 24) | (unsigned)s;
    }
}

// 512 threads; derives its own binBase by scanning binCur in LDS (no bin_scan kernel)
__global__ __launch_bounds__(512)
void bin_finalize(const unsigned* __restrict__ pairs, const int* __restrict__ binCur,
                  int* __restrict__ rowptr, int* __restrict__ csr_src,
                  int n, int nbins, int Etot) {
    int b = blockIdx.x;
    int t = threadIdx.x;
    __shared__ int h[256], s[256], cur[256];
    __shared__ int sb_base, sb_cnt;

    if (t < 256) s[t] = (t < nbins) ? binCur[t] : 0;
    __syncthreads();
    for (int o = 1; o < 256; o <<= 1) {
        int tv = (t >= o && t < 256) ? s[t - o] : 0;
        __syncthreads();
        if (t < 256) s[t] += tv;
        __syncthreads();
    }
    if (t == 0) {
        sb_cnt = binCur[b];
        sb_base = s[b] - sb_cnt;
        if (b == nbins - 1) rowptr[n] = Etot;
    }
    __syncthreads();
    int base = sb_base, cnt = sb_cnt;
    int lop = b * BINCAP;
    int d0 = b << BIN_SHIFT;
    int nd = min(256, n - d0);

    if (t < 256) h[t] = 0;
    __syncthreads();
    for (int i = lop + t; i < lop + cnt; i += 512)
        atomicAdd(&h[pairs[i] >> 24], 1);
    __syncthreads();
    if (t < 256) s[t] = h[t];
    __syncthreads();
    for (int o = 1; o < 256; o <<= 1) {
        int tv = (t >= o && t < 256) ? s[t - o] : 0;
        __syncthreads();
        if (t < 256) s[t] += tv;
        __syncthreads();
    }
    if (t < 256) {
        int excl = base + s[t] - h[t];
        if (t < nd) rowptr[d0 + t] = excl;
        cur[t] = excl;
    }
    __syncthreads();
    for (int i = lop + t; i < lop + cnt; i += 512) {
        unsigned pr = pairs[i];
        int p = atomicAdd(&cur[pr >> 24], 1);
        csr_src[p] = (int)(pr & 0xFFFFFF);
    }
}

// ------------- fused GAT aggregation: one wave per dst node -----------------
__global__ void gat_gather(const int* __restrict__ rowptr, const int* __restrict__ csr_src,
                           const float* __restrict__ ssrc, const float* __restrict__ sdst,
                           const unsigned short* __restrict__ hu, const float* __restrict__ bias,
                           unsigned* __restrict__ outh, int n) {
    __shared__ uint2 stage[4][64];
    int wv = threadIdx.x >> 6;
    int wid = (blockIdx.x * blockDim.x + threadIdx.x) >> 6;
    int lane = threadIdx.x & 63;
    if (wid >= n) return;
    int beg = rowptr[wid], end = rowptr[wid + 1];
    float sd = sdst[wid];
    int g = lane >> 4;
    int c = lane & 15;

    int src0 = 0; float v0 = -INFINITY;
    {
        int i = beg + lane;
        if (i < end) {
            src0 = csr_src[i];
            float t = ssrc[src0] + sd;
            v0 = t > 0.f ? t : NEG_SLOPE * t;
        }
    }
    float m = v0;
    for (int base = beg + 64; base < end; base += 64) {
        int i = base + lane;
        float s = -INFINITY;
        if (i < end) {
            float t = ssrc[csr_src[i]] + sd;
            s = t > 0.f ? t : NEG_SLOPE * t;
        }
        m = fmaxf(m, s);
    }
    #pragma unroll
    for (int o = 32; o; o >>= 1) m = fmaxf(m, __shfl_xor(m, o));

    float acc[8];
    #pragma unroll
    for (int k = 0; k < 8; ++k) acc[k] = 0.f;
    float den = 0.f;

    for (int base = beg; base < end; base += 64) {
        int cnt = min(64, end - base);
        float w = 0.f; int src = 0;
        if (base == beg) {
            src = src0;
            w = (lane < cnt) ? expf(v0 - m) : 0.f;
        } else {
            int i = base + lane;
            if (i < end) {
                src = csr_src[i];
                float t = ssrc[src] + sd;
                t = t > 0.f ? t : NEG_SLOPE * t;
                w = expf(t - m);
            }
        }
        den += w;
        stage[wv][lane] = make_uint2(__float_as_uint(w), (unsigned)src);
        asm volatile("s_waitcnt lgkmcnt(0)" ::: "memory");
        int steps = (cnt + 3) >> 2;
        #pragma unroll 4
        for (int j = 0; j < steps; ++j) {
            uint2 pr = stage[wv][j * 4 + g];
            float wj = __uint_as_float(pr.x);
            const uint4 hv = *(const uint4*)(hu + (size_t)pr.y * 128 + c * 8);
            FMAMIX_LO(acc[0], hv.x, wj); FMAMIX_HI(acc[1], hv.x, wj);
            FMAMIX_LO(acc[2], hv.y, wj); FMAMIX_HI(acc[3], hv.y, wj);
            FMAMIX_LO(acc[4], hv.z, wj); FMAMIX_HI(acc[5], hv.z, wj);
            FMAMIX_LO(acc[6], hv.w, wj); FMAMIX_HI(acc[7], hv.w, wj);
        }
    }
    #pragma unroll
    for (int o = 32; o; o >>= 1) den += __shfl_xor(den, o);
    #pragma unroll
    for (int k = 0; k < 8; ++k) {
        acc[k] += __shfl_xor(acc[k], 16);
        acc[k] += __shfl_xor(acc[k], 32);
    }
    if (g == 0) {
        float o8[8];
        #pragma unroll
        for (int k = 0; k < 8; ++k) {
            float v = acc[k] / den + bias[c * 8 + k];
            o8[k] = v > 0.f ? v : (expf(v) - 1.f);
        }
        uint4 u = make_uint4(pkh_rne(o8[0], o8[1]), pkh_rne(o8[2], o8[3]),
                             pkh_rne(o8[4], o8[5]), pkh_rne(o8[6], o8[7]));
        *(uint4*)(outh + (size_t)wid * 64 + c * 4) = u;
    }
}

// ------- pooling: G*16 blocks, uint4 (8ch) per thread, LDS reduce -----------
__global__ void pool_partial(const unsigned short* __restrict__ y, const int* __restrict__ batch,
                             float* __restrict__ gsum, int n) {
    int g = blockIdx.x >> 4, seg = blockIdx.x & 15;
    int lo = 0, hi = n;
    while (lo < hi) { int mid = (lo + hi) >> 1; if (batch[mid] < g) lo = mid + 1; else hi = mid; }
    int beg = lo;
    hi = n;
    while (lo < hi) { int mid = (lo + hi) >> 1; if (batch[mid] < g + 1) lo = mid + 1; else hi = mid; }
    int end = lo;

    int r  = threadIdx.x >> 4;    // 16 row-groups
    int c8 = threadIdx.x & 15;    // 16 channel-chunks of 8 f16
    float acc[8];
    #pragma unroll
    for (int j = 0; j < 8; ++j) acc[j] = 0.f;
    for (int node = beg + seg + (r << 4); node < end; node += 256) {
        f16x8 hv = *(const f16x8*)(y + (size_t)node * 128 + c8 * 8);
        #pragma unroll
        for (int j = 0; j < 8; ++j) acc[j] += (float)hv[j];
    }
    __shared__ float ls[16][128];
    #pragma unroll
    for (int j = 0; j < 8; ++j) ls[r][c8 * 8 + j] = acc[j];
    __syncthreads();
    int t = threadIdx.x;
    if (t < 128) {
        float s = 0.f;
        #pragma unroll
        for (int k = 0; k < 16; ++k) s += ls[k][t];
        atomicAdd(&gsum[g * 128 + t], s);
    }
}

__global__ void pool_final(const float* __restrict__ gsum, const int* __restrict__ batch,
                           const float* __restrict__ Wlin, const float* __restrict__ blin,
                           float* __restrict__ out, int n, int G) {
    __shared__ float Wl[128 * 32];
    __shared__ int cnts[64];
    int t = threadIdx.x;
    for (int i = t; i < 128 * 32; i += 256) Wl[i] = Wlin[i];
    if (t < G) {
        int g = t;
        int lo = 0, hi = n;
        while (lo < hi) { int mid = (lo + hi) >> 1; if (batch[mid] < g) lo = mid + 1; else hi = mid; }
        int beg = lo;
        hi = n;
        while (lo < hi) { int mid = (lo + hi) >> 1; if (batch[mid] < g + 1) lo = mid + 1; else hi = mid; }
        cnts[g] = lo - beg;
    }
    __syncthreads();
    for (int idx = t; idx < G * 32; idx += 256) {
        int g = idx >> 5, oc = idx & 31;
        int cnt = cnts[g];
        float o = 0.f;
        if (cnt > 0) {
            float inv = 1.f / (float)cnt;
            float acc = 0.f;
            #pragma unroll 8
            for (int k = 0; k < 128; ++k) acc += gsum[g * 128 + k] * Wl[k * 32 + oc];
            o = acc * inv + blin[oc];
        }
        out[idx] = o;
    }
}

extern "C" void kernel_launch(void* const* d_in, const int* in_sizes, int n_in,
                              void* d_out, int out_size, void* d_ws, size_t ws_size,
                              hipStream_t stream) {
    const float* pos  = (const float*)d_in[0];
    const int*   z    = (const int*)d_in[1];
    const int*   ei   = (const int*)d_in[2];
    const int*   batch= (const int*)d_in[3];
    const float* emb  = (const float*)d_in[4];
    const float* W1   = (const float*)d_in[5];
    const float* a1s  = (const float*)d_in[6];
    const float* a1d  = (const float*)d_in[7];
    const float* b1   = (const float*)d_in[8];
    const float* W2   = (const float*)d_in[9];
    const float* a2s  = (const float*)d_in[10];
    const float* a2d  = (const float*)d_in[11];
    const float* b2   = (const float*)d_in[12];
    const float* Wlin = (const float*)d_in[13];
    const float* blin = (const float*)d_in[14];

    const int N = in_sizes[0] / 3;        // 50000
    const int E = in_sizes[2] / 2;        // 1600000
    const int Etot = E + N;
    const int G = out_size / 32;          // 64
    const int nbins = ((N - 1) >> BIN_SHIFT) + 1;   // 196

    char* ws = (char*)d_ws;
    size_t pairsB = (size_t)nbins * BINCAP * sizeof(unsigned);   // 12.85MB, 256B-aligned
    unsigned* pairs = (unsigned*)ws;
    unsigned short* xh  = (unsigned short*)(ws + pairsB);        // f16 out1 / out2
    unsigned short* hbf = xh + (size_t)N * 128;                  // f16 h
    float* ssrc   = (float*)(hbf + (size_t)N * 128);
    float* sdst   = ssrc + N;
    int*   rowptr = (int*)(sdst + N);              // N+1
    int*   binCur = rowptr + N + 1;                // 256
    float* gsum   = (float*)(binCur + 256);        // G*128 (memset with binCur)
    int*   csrs   = (int*)(gsum + (size_t)G * 128);// Etot

    const int TB = 256;
    dim3 blk(TB);
    int gGemm  = (N + 63) / 64;
    int gGat   = (N + 3) / 4;
    int nchunk = (Etot + CHUNK - 1) / CHUNK;       // 807

    // ---------- CSR build (binCur + gsum zeroed in one memset) ----------
    hipMemsetAsync(binCur, 0, (256 + (size_t)G * 128) * sizeof(int), stream);
    bin_scatter<<<nchunk, blk, 0, stream>>>(ei, E, N, nbins, binCur, pairs);
    bin_finalize<<<nbins, dim3(512), 0, stream>>>(pairs, binCur, rowptr, csrs, N, nbins, Etot);

    // ---------- layer 1 (build_x fused into GEMM staging) ----------
    gemm128_mfma<true><<<gGemm, blk, 0, stream>>>(nullptr, pos, z, emb, W1, a1s, a1d,
                                                  hbf, ssrc, sdst, N);
    gat_gather<<<gGat, blk, 0, stream>>>(rowptr, csrs, ssrc, sdst, hbf, b1, (unsigned*)xh, N);

    // ---------- layer 2 ----------
    gemm128_mfma<false><<<gGemm, blk, 0, stream>>>(xh, nullptr, nullptr, nullptr, W2, a2s, a2d,
                                                   hbf, ssrc, sdst, N);
    gat_gather<<<gGat, blk, 0, stream>>>(rowptr, csrs, ssrc, sdst, hbf, b2, (unsigned*)xh, N);

    // ---------- pool ----------
    pool_partial<<<G * 16, blk, 0, stream>>>(xh, batch, gsum, N);
    pool_final<<<1, blk, 0, stream>>>(gsum, batch, Wlin, blin, (float*)d_out, N, G);
}

// Round 21
// 266.857 us; speedup vs baseline: 1.1375x; 1.0047x over previous
//
#include <hip/hip_runtime.h>
#include <math.h>

#define NEG_SLOPE 0.2f
#define BIN_SHIFT 8          // dst bin = dst >> 8  (196 bins for N=50000)
#define CHUNK 2048           // edges per block in bin_scatter (8/thread)
#define BINCAP 16384         // fixed pairs capacity per bin (32/thread @512)

typedef __fp16 f16x4 __attribute__((ext_vector_type(4)));
typedef __fp16 f16x8 __attribute__((ext_vector_type(8)));
typedef float  f32x4 __attribute__((ext_vector_type(4)));

__device__ __forceinline__ unsigned pkh_rne(float a, float b) {
    __fp16 ha = (__fp16)a, hb = (__fp16)b;
    unsigned short ua, ub;
    __builtin_memcpy(&ua, &ha, 2);
    __builtin_memcpy(&ub, &hb, 2);
    return (unsigned)ua | ((unsigned)ub << 16);
}

// acc += f16(lo/hi of h) * w   (f32 accumulate)
#define FMAMIX_LO(a, h, w) asm("v_fma_mix_f32 %0, %1, %2, %0 op_sel:[0,0,0] op_sel_hi:[1,0,0]" : "+v"(a) : "v"(h), "v"(w))
#define FMAMIX_HI(a, h, w) asm("v_fma_mix_f32 %0, %1, %2, %0 op_sel:[1,0,0] op_sel_hi:[1,0,0]" : "+v"(a) : "v"(h), "v"(w))

// ---- MFMA f16 GEMM with fused node_dots epilogue ---------------------------
template <bool BX>
__global__ __launch_bounds__(256)
void gemm128_mfma(const unsigned short* __restrict__ Xin,
                  const float* __restrict__ pos, const int* __restrict__ z,
                  const float* __restrict__ emb,
                  const float* __restrict__ W,
                  const float* __restrict__ a_s, const float* __restrict__ a_d,
                  unsigned short* __restrict__ Yh,
                  float* __restrict__ ssrc, float* __restrict__ sdst, int n) {
    __shared__ unsigned short WT[128 * 128];  // 32 KB
    __shared__ unsigned short Xh[64 * 128];   // 16 KB
    __shared__ float As[128], Ad[128];
    __shared__ int zl[64];
    int tid = threadIdx.x;
    if (tid < 128) As[tid] = a_s[tid];
    else           Ad[tid - 128] = a_d[tid - 128];
    int r0 = blockIdx.x * 64;
    if (BX && tid < 64) zl[tid] = (r0 + tid < n) ? z[r0 + tid] : 0;

    #pragma unroll
    for (int it = 0; it < 32; ++it) {
        int id = it * 256 + tid;
        int col = id & 127, kp = id >> 7;
        float w0 = W[(size_t)(2 * kp) * 128 + col];
        float w1 = W[(size_t)(2 * kp + 1) * 128 + col];
        int byte = (col * 256 + kp * 4) ^ ((col & 7) << 3);
        *(unsigned*)((char*)WT + byte) = pkh_rne(w0, w1);
    }
    if (BX) __syncthreads();   // zl ready
    #pragma unroll
    for (int it = 0; it < 16; ++it) {
        int id = it * 256 + tid;
        int row = id >> 6, c = id & 63;
        int grow = r0 + row;
        unsigned v;
        if (BX) {
            float f0 = 0.f, f1 = 0.f;
            if (grow < n) {
                int zn = zl[row];
                int k0 = 2 * c, k1 = 2 * c + 1;
                f0 = (k0 < 3) ? pos[(size_t)grow * 3 + k0] : emb[(size_t)zn * 125 + (k0 - 3)];
                f1 = (k1 < 3) ? pos[(size_t)grow * 3 + k1] : emb[(size_t)zn * 125 + (k1 - 3)];
            }
            v = pkh_rne(f0, f1);
        } else {
            v = (grow < n) ? *(const unsigned*)(Xin + (size_t)grow * 128 + 2 * c) : 0u;
        }
        int byte = (row * 256 + c * 4) ^ ((row & 7) << 3);
        *(unsigned*)((char*)Xh + byte) = v;
    }
    __syncthreads();

    int lane = tid & 63, wv = tid >> 6;
    int rL = (wv << 4) + (lane & 15);
    int kg = lane >> 4;
    f32x4 acc[8];
    #pragma unroll
    for (int t = 0; t < 8; ++t) acc[t] = (f32x4){0.f, 0.f, 0.f, 0.f};

    #pragma unroll
    for (int k0 = 0; k0 < 128; k0 += 32) {
        int abase = rL * 256;
        int aswz = (rL & 7) << 3;
        f16x4 alo = *(f16x4*)((char*)Xh + ((abase + (k0 + kg * 4) * 2) ^ aswz));
        f16x4 ahi = *(f16x4*)((char*)Xh + ((abase + (k0 + 16 + kg * 4) * 2) ^ aswz));
        f16x8 a = {alo[0], alo[1], alo[2], alo[3], ahi[0], ahi[1], ahi[2], ahi[3]};
        #pragma unroll
        for (int t = 0; t < 8; ++t) {
            int colL = (t << 4) + (lane & 15);
            int bbase = colL * 256;
            int bswz = (colL & 7) << 3;
            f16x4 blo = *(f16x4*)((char*)WT + ((bbase + (k0 + kg * 4) * 2) ^ bswz));
            f16x4 bhi = *(f16x4*)((char*)WT + ((bbase + (k0 + 16 + kg * 4) * 2) ^ bswz));
            f16x8 b = {blo[0], blo[1], blo[2], blo[3], bhi[0], bhi[1], bhi[2], bhi[3]};
            acc[t] = __builtin_amdgcn_mfma_f32_16x16x32_f16(a, b, acc[t], 0, 0, 0);
        }
    }

    int rowBase = r0 + (wv << 4) + kg * 4;
    float ds[4] = {0.f, 0.f, 0.f, 0.f}, dd[4] = {0.f, 0.f, 0.f, 0.f};
    #pragma unroll
    for (int t = 0; t < 8; ++t) {
        int colA = (t << 4) + (lane & 15);
        float as = As[colA], ad = Ad[colA];
        #pragma unroll
        for (int i = 0; i < 4; ++i) {
            int rowA = rowBase + i;
            if (rowA < n) {
                __fp16 hv = (__fp16)acc[t][i];
                *(__fp16*)(Yh + (size_t)rowA * 128 + colA) = hv;
            }
            ds[i] += acc[t][i] * as;
            dd[i] += acc[t][i] * ad;
        }
    }
    #pragma unroll
    for (int o = 1; o < 16; o <<= 1) {
        #pragma unroll
        for (int i = 0; i < 4; ++i) {
            ds[i] += __shfl_xor(ds[i], o);
            dd[i] += __shfl_xor(dd[i], o);
        }
    }
    if ((lane & 15) == 0) {
        #pragma unroll
        for (int i = 0; i < 4; ++i) {
            int rowA = rowBase + i;
            if (rowA < n) { ssrc[rowA] = ds[i]; sdst[rowA] = dd[i]; }
        }
    }
}

// ------------- CSR build: fixed-capacity bins, register-staged (1 read) -----

// pairs packed: (dst & 255) << 24 | src; bin b region at b*BINCAP; binCur = count
__global__ void bin_scatter(const int* __restrict__ ei, int E, int n, int nbins,
                            int* __restrict__ binCursor, unsigned* __restrict__ pairs) {
    __shared__ int h[256], cur[256];
    int t = threadIdx.x;
    h[t] = 0;
    __syncthreads();
    int lo = blockIdx.x * CHUNK, hi = min(lo + CHUNK, E + n);
    // stage this thread's edges (<=8) in registers: one global read of ei
    int es[8], ed[8];
    int cntE = 0;
    #pragma unroll
    for (int k = 0; k < 8; ++k) {
        int e = lo + t + k * 256;
        if (e < hi) {
            int s, d;
            if (e < E) { s = ei[e]; d = ei[E + e]; } else { s = d = e - E; }
            es[cntE] = s; ed[cntE] = d; ++cntE;
            atomicAdd(&h[d >> BIN_SHIFT], 1);
        }
    }
    __syncthreads();
    if (t < nbins) cur[t] = (t << 14) + (h[t] ? atomicAdd(&binCursor[t], h[t]) : 0);
    __syncthreads();
    for (int k = 0; k < cntE; ++k) {
        int p = atomicAdd(&cur[ed[k] >> BIN_SHIFT], 1);
        pairs[p] = ((unsigned)(ed[k] & 255) << 24) | (unsigned)es[k];
    }
}

// 512 threads; derives binBase by scanning binCur in LDS; pairs staged in regs.
__global__ __launch_bounds__(512)
void bin_finalize(const unsigned* __restrict__ pairs, const int* __restrict__ binCur,
                  int* __restrict__ rowptr, int* __restrict__ csr_src,
                  int n, int nbins, int Etot) {
    int b = blockIdx.x;
    int t = threadIdx.x;
    __shared__ int h[256], s[256], cur[256];
    __shared__ int sb_base, sb_cnt;

    if (t < 256) s[t] = (t < nbins) ? binCur[t] : 0;
    __syncthreads();
    for (int o = 1; o < 256; o <<= 1) {
        int tv = (t >= o && t < 256) ? s[t - o] : 0;
        __syncthreads();
        if (t < 256) s[t] += tv;
        __syncthreads();
    }
    if (t == 0) {
        sb_cnt = binCur[b];
        sb_base = s[b] - sb_cnt;
        if (b == nbins - 1) rowptr[n] = Etot;
    }
    __syncthreads();
    int base = sb_base, cnt = sb_cnt;
    int lop = b * BINCAP;
    int d0 = b << BIN_SHIFT;
    int nd = min(256, n - d0);

    // stage this thread's pairs (<=32) in registers: one global read of pairs
    unsigned pv[32];
    int cntP = 0;
    for (int i = lop + t; i < lop + cnt; i += 512) pv[cntP++] = pairs[i];

    if (t < 256) h[t] = 0;
    __syncthreads();
    for (int k = 0; k < cntP; ++k) atomicAdd(&h[pv[k] >> 24], 1);
    __syncthreads();
    if (t < 256) s[t] = h[t];
    __syncthreads();
    for (int o = 1; o < 256; o <<= 1) {
        int tv = (t >= o && t < 256) ? s[t - o] : 0;
        __syncthreads();
        if (t < 256) s[t] += tv;
        __syncthreads();
    }
    if (t < 256) {
        int excl = base + s[t] - h[t];
        if (t < nd) rowptr[d0 + t] = excl;
        cur[t] = excl;
    }
    __syncthreads();
    for (int k = 0; k < cntP; ++k) {
        unsigned pr = pv[k];
        int p = atomicAdd(&cur[pr >> 24], 1);
        csr_src[p] = (int)(pr & 0xFFFFFF);
    }
}

// ------------- fused GAT aggregation: one wave per dst node -----------------
__global__ void gat_gather(const int* __restrict__ rowptr, const int* __restrict__ csr_src,
                           const float* __restrict__ ssrc, const float* __restrict__ sdst,
                           const unsigned short* __restrict__ hu, const float* __restrict__ bias,
                           unsigned* __restrict__ outh, int n) {
    __shared__ uint2 stage[4][64];
    int wv = threadIdx.x >> 6;
    int wid = (blockIdx.x * blockDim.x + threadIdx.x) >> 6;
    int lane = threadIdx.x & 63;
    if (wid >= n) return;
    int beg = rowptr[wid], end = rowptr[wid + 1];
    float sd = sdst[wid];
    int g = lane >> 4;
    int c = lane & 15;

    int src0 = 0; float v0 = -INFINITY;
    {
        int i = beg + lane;
        if (i < end) {
            src0 = csr_src[i];
            float t = ssrc[src0] + sd;
            v0 = t > 0.f ? t : NEG_SLOPE * t;
        }
    }
    float m = v0;
    for (int base = beg + 64; base < end; base += 64) {
        int i = base + lane;
        float s = -INFINITY;
        if (i < end) {
            float t = ssrc[csr_src[i]] + sd;
            s = t > 0.f ? t : NEG_SLOPE * t;
        }
        m = fmaxf(m, s);
    }
    #pragma unroll
    for (int o = 32; o; o >>= 1) m = fmaxf(m, __shfl_xor(m, o));

    float acc[8];
    #pragma unroll
    for (int k = 0; k < 8; ++k) acc[k] = 0.f;
    float den = 0.f;

    for (int base = beg; base < end; base += 64) {
        int cnt = min(64, end - base);
        float w = 0.f; int src = 0;
        if (base == beg) {
            src = src0;
            w = (lane < cnt) ? expf(v0 - m) : 0.f;
        } else {
            int i = base + lane;
            if (i < end) {
                src = csr_src[i];
                float t = ssrc[src] + sd;
                t = t > 0.f ? t : NEG_SLOPE * t;
                w = expf(t - m);
            }
        }
        den += w;
        stage[wv][lane] = make_uint2(__float_as_uint(w), (unsigned)src);
        asm volatile("s_waitcnt lgkmcnt(0)" ::: "memory");
        int steps = (cnt + 3) >> 2;
        #pragma unroll 4
        for (int j = 0; j < steps; ++j) {
            uint2 pr = stage[wv][j * 4 + g];
            float wj = __uint_as_float(pr.x);
            const uint4 hv = *(const uint4*)(hu + (size_t)pr.y * 128 + c * 8);
            FMAMIX_LO(acc[0], hv.x, wj); FMAMIX_HI(acc[1], hv.x, wj);
            FMAMIX_LO(acc[2], hv.y, wj); FMAMIX_HI(acc[3], hv.y, wj);
            FMAMIX_LO(acc[4], hv.z, wj); FMAMIX_HI(acc[5], hv.z, wj);
            FMAMIX_LO(acc[6], hv.w, wj); FMAMIX_HI(acc[7], hv.w, wj);
        }
    }
    #pragma unroll
    for (int o = 32; o; o >>= 1) den += __shfl_xor(den, o);
    #pragma unroll
    for (int k = 0; k < 8; ++k) {
        acc[k] += __shfl_xor(acc[k], 16);
        acc[k] += __shfl_xor(acc[k], 32);
    }
    if (g == 0) {
        float o8[8];
        #pragma unroll
        for (int k = 0; k < 8; ++k) {
            float v = acc[k] / den + bias[c * 8 + k];
            o8[k] = v > 0.f ? v : (expf(v) - 1.f);
        }
        uint4 u = make_uint4(pkh_rne(o8[0], o8[1]), pkh_rne(o8[2], o8[3]),
                             pkh_rne(o8[4], o8[5]), pkh_rne(o8[6], o8[7]));
        *(uint4*)(outh + (size_t)wid * 64 + c * 4) = u;
    }
}

// ------- pooling: G*16 blocks, f16x8 per thread, LDS reduce -----------------
__global__ void pool_partial(const unsigned short* __restrict__ y, const int* __restrict__ batch,
                             float* __restrict__ gsum, int n) {
    int g = blockIdx.x >> 4, seg = blockIdx.x & 15;
    int lo = 0, hi = n;
    while (lo < hi) { int mid = (lo + hi) >> 1; if (batch[mid] < g) lo = mid + 1; else hi = mid; }
    int beg = lo;
    hi = n;
    while (lo < hi) { int mid = (lo + hi) >> 1; if (batch[mid] < g + 1) lo = mid + 1; else hi = mid; }
    int end = lo;

    int r  = threadIdx.x >> 4;    // 16 row-groups
    int c8 = threadIdx.x & 15;    // 16 channel-chunks of 8 f16
    float acc[8];
    #pragma unroll
    for (int j = 0; j < 8; ++j) acc[j] = 0.f;
    for (int node = beg + seg + (r << 4); node < end; node += 256) {
        f16x8 hv = *(const f16x8*)(y + (size_t)node * 128 + c8 * 8);
        #pragma unroll
        for (int j = 0; j < 8; ++j) acc[j] += (float)hv[j];
    }
    __shared__ float ls[16][128];
    #pragma unroll
    for (int j = 0; j < 8; ++j) ls[r][c8 * 8 + j] = acc[j];
    __syncthreads();
    int t = threadIdx.x;
    if (t < 128) {
        float s = 0.f;
        #pragma unroll
        for (int k = 0; k < 16; ++k) s += ls[k][t];
        atomicAdd(&gsum[g * 128 + t], s);
    }
}

__global__ void pool_final(const float* __restrict__ gsum, const int* __restrict__ batch,
                           const float* __restrict__ Wlin, const float* __restrict__ blin,
                           float* __restrict__ out, int n, int G) {
    __shared__ float Wl[128 * 32];
    __shared__ int cnts[64];
    int t = threadIdx.x;
    for (int i = t; i < 128 * 32; i += 256) Wl[i] = Wlin[i];
    if (t < G) {
        int g = t;
        int lo = 0, hi = n;
        while (lo < hi) { int mid = (lo + hi) >> 1; if (batch[mid] < g) lo = mid + 1; else hi = mid; }
        int beg = lo;
        hi = n;
        while (lo < hi) { int mid = (lo + hi) >> 1; if (batch[mid] < g + 1) lo = mid + 1; else hi = mid; }
        cnts[g] = lo - beg;
    }
    __syncthreads();
    for (int idx = t; idx < G * 32; idx += 256) {
        int g = idx >> 5, oc = idx & 31;
        int cnt = cnts[g];
        float o = 0.f;
        if (cnt > 0) {
            float inv = 1.f / (float)cnt;
            float acc = 0.f;
            #pragma unroll 8
            for (int k = 0; k < 128; ++k) acc += gsum[g * 128 + k] * Wl[k * 32 + oc];
            o = acc * inv + blin[oc];
        }
        out[idx] = o;
    }
}

extern "C" void kernel_launch(void* const* d_in, const int* in_sizes, int n_in,
                              void* d_out, int out_size, void* d_ws, size_t ws_size,
                              hipStream_t stream) {
    const float* pos  = (const float*)d_in[0];
    const int*   z    = (const int*)d_in[1];
    const int*   ei   = (const int*)d_in[2];
    const int*   batch= (const int*)d_in[3];
    const float* emb  = (const float*)d_in[4];
    const float* W1   = (const float*)d_in[5];
    const float* a1s  = (const float*)d_in[6];
    const float* a1d  = (const float*)d_in[7];
    const float* b1   = (const float*)d_in[8];
    const float* W2   = (const float*)d_in[9];
    const float* a2s  = (const float*)d_in[10];
    const float* a2d  = (const float*)d_in[11];
    const float* b2   = (const float*)d_in[12];
    const float* Wlin = (const float*)d_in[13];
    const float* blin = (const float*)d_in[14];

    const int N = in_sizes[0] / 3;        // 50000
    const int E = in_sizes[2] / 2;        // 1600000
    const int Etot = E + N;
    const int G = out_size / 32;          // 64
    const int nbins = ((N - 1) >> BIN_SHIFT) + 1;   // 196

    char* ws = (char*)d_ws;
    size_t pairsB = (size_t)nbins * BINCAP * sizeof(unsigned);   // 12.85MB, 256B-aligned
    unsigned* pairs = (unsigned*)ws;
    unsigned short* xh  = (unsigned short*)(ws + pairsB);        // f16 out1 / out2
    unsigned short* hbf = xh + (size_t)N * 128;                  // f16 h
    float* ssrc   = (float*)(hbf + (size_t)N * 128);
    float* sdst   = ssrc + N;
    int*   rowptr = (int*)(sdst + N);              // N+1
    int*   binCur = rowptr + N + 1;                // 256
    float* gsum   = (float*)(binCur + 256);        // G*128 (memset with binCur)
    int*   csrs   = (int*)(gsum + (size_t)G * 128);// Etot

    const int TB = 256;
    dim3 blk(TB);
    int gGemm  = (N + 63) / 64;
    int gGat   = (N + 3) / 4;
    int nchunk = (Etot + CHUNK - 1) / CHUNK;       // 807

    // ---------- CSR build (binCur + gsum zeroed in one memset) ----------
    hipMemsetAsync(binCur, 0, (256 + (size_t)G * 128) * sizeof(int), stream);
    bin_scatter<<<nchunk, blk, 0, stream>>>(ei, E, N, nbins, binCur, pairs);
    bin_finalize<<<nbins, dim3(512), 0, stream>>>(pairs, binCur, rowptr, csrs, N, nbins, Etot);

    // ---------- layer 1 (build_x fused into GEMM staging) ----------
    gemm128_mfma<true><<<gGemm, blk, 0, stream>>>(nullptr, pos, z, emb, W1, a1s, a1d,
                                                  hbf, ssrc, sdst, N);
    gat_gather<<<gGat, blk, 0, stream>>>(rowptr, csrs, ssrc, sdst, hbf, b1, (unsigned*)xh, N);

    // ---------- layer 2 ----------
    gemm128_mfma<false><<<gGemm, blk, 0, stream>>>(xh, nullptr, nullptr, nullptr, W2, a2s, a2d,
                                                   hbf, ssrc, sdst, N);
    gat_gather<<<gGat, blk, 0, stream>>>(rowptr, csrs, ssrc, sdst, hbf, b2, (unsigned*)xh, N);

    // ---------- pool ----------
    pool_partial<<<G * 16, blk, 0, stream>>>(xh, batch, gsum, N);
    pool_final<<<1, blk, 0, stream>>>(gsum, batch, Wlin, blin, (float*)d_out, N, G);
}